// Round 9
// baseline (257.972 us; speedup 1.0000x reference)
//
#include <hip/hip_runtime.h>

#define ROWS 4096
#define NCOL 8192
#define ROW_F4 (NCOL / 4)                    // 2048 float4 per row
#define CHUNK_F4 64                          // 64 float4 = 256 elements per chunk
#define CHUNKS_PER_ROW (ROW_F4 / CHUNK_F4)   // 32

// ---- K1: grid-stride stream (copy-pattern): read x, write out=0, chunk-max ----
#define K1_BLOCKS 2048
#define K1_THREADS 256
#define K1_STRIDE ((size_t)K1_BLOCKS * K1_THREADS)      // 524288 float4
#define TOTAL_F4 ((size_t)ROWS * ROW_F4)                // 8388608
#define K1_ITERS (TOTAL_F4 / K1_STRIDE)                 // 16

__global__ __launch_bounds__(K1_THREADS, 8)
void streamscan_kernel(const float* __restrict__ x, float* __restrict__ out,
                       float* __restrict__ cmax) {
    const float4* __restrict__ xr = (const float4*)x;
    float4* __restrict__ outr     = (float4*)out;
    const size_t i0 = (size_t)blockIdx.x * K1_THREADS + threadIdx.x;
    const int is_lane0 = ((threadIdx.x & 63) == 0);
    const float4 z = make_float4(0.0f, 0.0f, 0.0f, 0.0f);

#pragma unroll 4
    for (int k = 0; k < (int)K1_ITERS; ++k) {
        const size_t i = i0 + (size_t)k * K1_STRIDE;
        float4 q = xr[i];
        outr[i] = z;                               // fused zero-fill of out
        float m = fmaxf(fmaxf(q.x, q.y), fmaxf(q.z, q.w));
#pragma unroll
        for (int off = 32; off > 0; off >>= 1)
            m = fmaxf(m, __shfl_xor(m, off, 64));
        if (is_lane0) cmax[i >> 6] = m;            // one float per 256-element chunk
    }
}

// ---- K23: per-row tau from chunk-maxes + sparse fixup (one wave per row) ----
__global__ __launch_bounds__(64)
void taufix_kernel(const float* __restrict__ x, float* __restrict__ out,
                   const float* __restrict__ cmax) {
    const int row = blockIdx.x;
    const int l   = threadIdx.x;                   // 0..63
    __shared__ float cand[256];
    __shared__ int   scnt;
    if (l == 0) scnt = 0;

    // row max from the 32 chunk maxes
    const float cl = (l < 32) ? cmax[row * CHUNKS_PER_ROW + l] : -INFINITY;
    float rm = cl;
#pragma unroll
    for (int off = 32; off > 0; off >>= 1) rm = fmaxf(rm, __shfl_xor(rm, off, 64));
    const float thr = rm - 1.0f;                   // tau* >= rowmax - 1

    const float4* __restrict__ xrow = (const float4*)(x + (size_t)row * NCOL);

    // scan only chunks that can contain values > thr (expected ~5-17 of 32)
    float c0 = -INFINITY, c1 = -INFINITY, c2 = -INFINITY, c3 = -INFINITY;
    float e  = -INFINITY;                          // max of values evicted from top-4
#define INS(qv) do {                                    \
        float n = (qv), mx;                             \
        mx = fmaxf(c0, n); n = fminf(c0, n); c0 = mx;   \
        mx = fmaxf(c1, n); n = fminf(c1, n); c1 = mx;   \
        mx = fmaxf(c2, n); n = fminf(c2, n); c2 = mx;   \
        mx = fmaxf(c3, n); n = fminf(c3, n); c3 = mx;   \
        e = fmaxf(e, n);                                \
    } while (0)
    unsigned long long mm = __ballot(cl > thr);    // lanes >= 32 contribute 0
    while (mm) {
        const int c = __builtin_ctzll(mm); mm &= mm - 1;
        float4 q = xrow[c * CHUNK_F4 + l];         // 64 lanes x 4 el = whole chunk
        INS(q.x); INS(q.y); INS(q.z); INS(q.w);
    }
#undef INS

    // push candidates (> thr) -- structurally <= 64*4 = 256, never overflows
    __syncthreads();
    if (c0 > thr) { int p = atomicAdd(&scnt, 1); cand[p] = c0; }
    if (c1 > thr) { int p = atomicAdd(&scnt, 1); cand[p] = c1; }
    if (c2 > thr) { int p = atomicAdd(&scnt, 1); cand[p] = c2; }
    if (c3 > thr) { int p = atomicAdd(&scnt, 1); cand[p] = c3; }
    __syncthreads();
    const int k0 = scnt;

    // shuffle-only Michelot on the candidate list (identical across lanes)
    float t = thr;
    {
        const float p0 = (l       < k0) ? cand[l      ] : -INFINITY;
        const float p1 = (l + 64  < k0) ? cand[l + 64 ] : -INFINITY;
        const float p2 = (l + 128 < k0) ? cand[l + 128] : -INFINITY;
        const float p3 = (l + 192 < k0) ? cand[l + 192] : -INFINITY;
        int prev = -1;
        for (int it = 0; it < 64; ++it) {
            float s = 0.0f; int k = 0;
            if (p0 > t) { s += p0; ++k; }
            if (p1 > t) { s += p1; ++k; }
            if (p2 > t) { s += p2; ++k; }
            if (p3 > t) { s += p3; ++k; }
#pragma unroll
            for (int off = 32; off > 0; off >>= 1) {
                s += __shfl_xor(s, off, 64);
                k += __shfl_xor(k, off, 64);
            }
            if (k == prev) break;                  // support stable => fixed point
            prev = k;
            t = (s - 1.0f) / (float)k;
        }
    }

    // validity: any evicted value above t means candidates may be incomplete
    float be = e;
#pragma unroll
    for (int off = 32; off > 0; off >>= 1) be = fmaxf(be, __shfl_xor(be, off, 64));
    if (be > t) {
        // exact fallback (rare): full-row Michelot; t is a valid lower bound
        int prev = -1;
        for (int it = 0; it < 200; ++it) {
            float s = 0.0f; int k = 0;
            for (int j = 0; j < CHUNKS_PER_ROW; ++j) {
                float4 q = xrow[j * CHUNK_F4 + l];
                if (q.x > t) { s += q.x; ++k; }
                if (q.y > t) { s += q.y; ++k; }
                if (q.z > t) { s += q.z; ++k; }
                if (q.w > t) { s += q.w; ++k; }
            }
#pragma unroll
            for (int off = 32; off > 0; off >>= 1) {
                s += __shfl_xor(s, off, 64);
                k += __shfl_xor(k, off, 64);
            }
            if (k == prev) break;
            prev = k;
            t = (s - 1.0f) / (float)k;
        }
    }

    // sparse fixup: only chunks that can contain support (out pre-zeroed by K1;
    // same-stream kernel ordering guarantees the zeros landed first)
    unsigned long long fm = __ballot(cl > t);
    while (fm) {
        const int c = __builtin_ctzll(fm); fm &= fm - 1;
        float4 q = xrow[c * CHUNK_F4 + l];
        const size_t base = (size_t)row * NCOL + (size_t)c * 256 + (size_t)l * 4;
        if (q.x > t) out[base    ] = q.x - t;
        if (q.y > t) out[base + 1] = q.y - t;
        if (q.z > t) out[base + 2] = q.z - t;
        if (q.w > t) out[base + 3] = q.w - t;
    }
}

extern "C" void kernel_launch(void* const* d_in, const int* in_sizes, int n_in,
                              void* d_out, int out_size, void* d_ws, size_t ws_size,
                              hipStream_t stream) {
    const float* x = (const float*)d_in[0];
    float* out = (float*)d_out;
    float* cmax = (float*)d_ws;   // 131072 floats = 512 KiB workspace

    streamscan_kernel<<<K1_BLOCKS, K1_THREADS, 0, stream>>>(x, out, cmax);
    taufix_kernel<<<ROWS, 64, 0, stream>>>(x, out, cmax);
}